// Round 1
// baseline (7759.940 us; speedup 1.0000x reference)
//
#include <hip/hip_runtime.h>
#include <math.h>

#define N_USERS 100000
#define N_ITEMS 50000
#define N_NODES 150000
#define EMB 64
#define NI 128
#define NUM_EDGES 4000000

// ---------------- normalization ----------------

__global__ void deg_kernel(const int* __restrict__ h, float* __restrict__ deg) {
    int i = blockIdx.x * blockDim.x + threadIdx.x;
    if (i < NUM_EDGES) atomicAdd(&deg[h[i]], 1.0f);
}

__global__ void dinv_kernel(float* __restrict__ deg) {
    int i = blockIdx.x * blockDim.x + threadIdx.x;
    if (i < N_NODES) {
        float d = deg[i];
        deg[i] = (d > 0.0f) ? rsqrtf(d) : 0.0f;
    }
}

__global__ void gvals_kernel(const int* __restrict__ h, const int* __restrict__ t,
                             const float* __restrict__ dinv, float* __restrict__ g) {
    int i = blockIdx.x * blockDim.x + threadIdx.x;
    if (i < NUM_EDGES) g[i] = dinv[h[i]] * dinv[t[i]];
}

// ---------------- init: embs = concat(user,item); acc(d_out) = embs ----------------

__global__ void init_kernel(const float* __restrict__ ue, const float* __restrict__ ie,
                            float* __restrict__ embs, float* __restrict__ acc) {
    int i = blockIdx.x * blockDim.x + threadIdx.x;  // over float4 elements
    const int uelems = N_USERS * EMB / 4;           // 1.6M
    const int total  = N_NODES * EMB / 4;           // 2.4M
    if (i < total) {
        float4 v = (i < uelems) ? ((const float4*)ue)[i] : ((const float4*)ie)[i - uelems];
        ((float4*)embs)[i] = v;
        ((float4*)acc)[i]  = v;
    }
}

// ---------------- SpMM: gnn[h] += g * embs[t], atomic scatter ----------------
// 16 threads per edge, each handles a float4 chunk of the 64-wide row.

__global__ void spmm_kernel(const int* __restrict__ h, const int* __restrict__ t,
                            const float* __restrict__ g, const float* __restrict__ embs,
                            float* __restrict__ out) {
    int tid = blockIdx.x * blockDim.x + threadIdx.x;
    int e = tid >> 4;
    int c = tid & 15;
    if (e < NUM_EDGES) {
        int hn = h[e], tn = t[e];
        float gv = g[e];
        float4 v = ((const float4*)embs)[tn * 16 + c];
        float* o = out + (size_t)hn * EMB + c * 4;
        atomicAdd(o + 0, v.x * gv);
        atomicAdd(o + 1, v.y * gv);
        atomicAdd(o + 2, v.z * gv);
        atomicAdd(o + 3, v.w * gv);
    }
}

// ---------------- intent head + combine ----------------
// new = gnn[row] + softmax(embs[row] @ W) @ W^T ; embs[row] = new ;
// acc[row] = (acc[row] + new) * scale
// One wave per row, 4 rows per 256-thread block. W^T staged in LDS padded to 65
// so both access phases are bank-conflict-free (2-way max, free on CDNA4).

__global__ __launch_bounds__(256) void intent_kernel(const float* __restrict__ W,
                                                     const float* __restrict__ gnn,
                                                     float* __restrict__ embs,
                                                     float* __restrict__ acc,
                                                     float scale) {
    __shared__ float Wt[NI * 65];    // Wt[c*65+d] = W[d*128+c]
    __shared__ float esm[4][EMB];
    __shared__ float pr[4][NI];

    for (int i = threadIdx.x; i < EMB * NI; i += blockDim.x) {
        int d = i >> 7, c = i & 127;
        Wt[c * 65 + d] = W[i];
    }
    __syncthreads();

    int wave = threadIdx.x >> 6;
    int lane = threadIdx.x & 63;
    int row  = blockIdx.x * 4 + wave;   // grid exactly covers 150000 rows

    esm[wave][lane] = embs[row * EMB + lane];
    __syncthreads();

    // scores: lane owns intent columns {lane, lane+64}
    float s0 = 0.0f, s1 = 0.0f;
    const float* w0 = &Wt[lane * 65];
    const float* w1 = &Wt[(lane + 64) * 65];
    const float* er = esm[wave];
#pragma unroll 8
    for (int d = 0; d < EMB; ++d) {
        float ed = er[d];
        s0 = fmaf(ed, w0[d], s0);
        s1 = fmaf(ed, w1[d], s1);
    }

    // softmax over 128 (wave-wide reduce across 64 lanes)
    float m = fmaxf(s0, s1);
    for (int o = 32; o > 0; o >>= 1) m = fmaxf(m, __shfl_xor(m, o));
    float e0 = __expf(s0 - m), e1 = __expf(s1 - m);
    float sum = e0 + e1;
    for (int o = 32; o > 0; o >>= 1) sum += __shfl_xor(sum, o);
    float inv = 1.0f / sum;
    pr[wave][lane]      = e0 * inv;
    pr[wave][lane + 64] = e1 * inv;
    __syncthreads();

    // output: lane owns dim d = lane: o_d = sum_c p_c * W[d][c]
    float o = 0.0f;
    const float* pw = pr[wave];
#pragma unroll 8
    for (int c = 0; c < NI; ++c) o = fmaf(pw[c], Wt[c * 65 + lane], o);

    int idx = row * EMB + lane;
    float nv = gnn[idx] + o;
    embs[idx] = nv;
    acc[idx] = (acc[idx] + nv) * scale;
}

// ---------------- launch ----------------

extern "C" void kernel_launch(void* const* d_in, const int* in_sizes, int n_in,
                              void* d_out, int out_size, void* d_ws, size_t ws_size,
                              hipStream_t stream) {
    const float* ue = (const float*)d_in[0];   // user_emb  (100000*64)
    const float* ie = (const float*)d_in[1];   // item_emb  (50000*64)
    const float* W  = (const float*)d_in[2];   // intents   (64*128)
    const int*   h  = (const int*)d_in[3];     // h_idx     (4M)
    const int*   t  = (const int*)d_in[4];     // t_idx     (4M)
    float* out = (float*)d_out;                // 150000*64, also the running sum

    float* ws   = (float*)d_ws;
    float* dinv = ws;                 // 150016 floats (deg, then rsqrt in place)
    float* g    = ws + 150016;        // 4,000,000
    float* embs = ws + 4150016;       // 9,600,000
    float* gnn  = ws + 13750016;      // 9,600,000

    hipMemsetAsync(dinv, 0, 150016 * sizeof(float), stream);
    deg_kernel<<<(NUM_EDGES + 255) / 256, 256, 0, stream>>>(h, dinv);
    dinv_kernel<<<(N_NODES + 255) / 256, 256, 0, stream>>>(dinv);
    gvals_kernel<<<(NUM_EDGES + 255) / 256, 256, 0, stream>>>(h, t, dinv, g);
    init_kernel<<<(N_NODES * EMB / 4 + 255) / 256, 256, 0, stream>>>(ue, ie, embs, out);

    for (int layer = 0; layer < 2; ++layer) {
        hipMemsetAsync(gnn, 0, (size_t)N_NODES * EMB * sizeof(float), stream);
        spmm_kernel<<<NUM_EDGES * 16 / 256, 256, 0, stream>>>(h, t, g, embs, gnn);
        float scale = (layer == 1) ? (1.0f / 3.0f) : 1.0f;
        intent_kernel<<<N_NODES / 4, 256, 0, stream>>>(W, gnn, embs, out, scale);
    }
}

// Round 2
// 1696.250 us; speedup vs baseline: 4.5748x; 4.5748x over previous
//
#include <hip/hip_runtime.h>
#include <math.h>

#define N_USERS 100000
#define N_ITEMS 50000
#define N_NODES 150000
#define EMB 64
#define NI 128
#define NUM_EDGES 4000000
#define NPAD 150016          // 586 * 256, padded node count for the scan
#define NBLK 586             // NPAD / 256

// ---------------- CSR build ----------------

__global__ void count_kernel(const int* __restrict__ h, int* __restrict__ cnt) {
    int i = blockIdx.x * blockDim.x + threadIdx.x;
    if (i < NUM_EDGES) atomicAdd(&cnt[h[i]], 1);
}

// per-block sums of cnt (586 blocks x 256)
__global__ __launch_bounds__(256) void blocksum_kernel(const int* __restrict__ cnt,
                                                       int* __restrict__ bsum) {
    __shared__ int s[256];
    int tid = threadIdx.x;
    s[tid] = cnt[blockIdx.x * 256 + tid];
    __syncthreads();
    for (int off = 128; off > 0; off >>= 1) {
        if (tid < off) s[tid] += s[tid + off];
        __syncthreads();
    }
    if (tid == 0) bsum[blockIdx.x] = s[0];
}

// exclusive scan of the 586 block sums, single block of 1024
__global__ __launch_bounds__(1024) void scanpart_kernel(int* __restrict__ bsum) {
    __shared__ int s[1024];
    int tid = threadIdx.x;
    int v = (tid < NBLK) ? bsum[tid] : 0;
    s[tid] = v;
    __syncthreads();
    for (int off = 1; off < 1024; off <<= 1) {
        int t = (tid >= off) ? s[tid - off] : 0;
        __syncthreads();
        s[tid] += t;
        __syncthreads();
    }
    if (tid < NBLK) bsum[tid] = s[tid] - v;   // exclusive
}

// row_ptr = exclusive scan of cnt; cursor = row_ptr; dinv = rsqrt(cnt)
__global__ __launch_bounds__(256) void finalize_kernel(const int* __restrict__ cnt,
                                                       const int* __restrict__ bsum,
                                                       int* __restrict__ row_ptr,
                                                       int* __restrict__ cursor,
                                                       float* __restrict__ dinv) {
    __shared__ int s[256];
    int tid = threadIdx.x;
    int i = blockIdx.x * 256 + tid;
    int c = cnt[i];
    s[tid] = c;
    __syncthreads();
    for (int off = 1; off < 256; off <<= 1) {
        int t = (tid >= off) ? s[tid - off] : 0;
        __syncthreads();
        s[tid] += t;
        __syncthreads();
    }
    int rp = bsum[blockIdx.x] + s[tid] - c;   // exclusive prefix
    row_ptr[i] = rp;
    cursor[i] = rp;
    dinv[i] = (c > 0) ? rsqrtf((float)c) : 0.0f;
}

__global__ void scatter_kernel(const int* __restrict__ h, const int* __restrict__ t,
                               int* __restrict__ cursor, int* __restrict__ col) {
    int e = blockIdx.x * blockDim.x + threadIdx.x;
    if (e < NUM_EDGES) {
        int p = atomicAdd(&cursor[h[e]], 1);
        col[p] = t[e];
    }
}

// ---------------- init: embs = concat(user,item); acc(d_out) = embs ----------------

__global__ void init_kernel(const float* __restrict__ ue, const float* __restrict__ ie,
                            float* __restrict__ embs, float* __restrict__ acc) {
    int i = blockIdx.x * blockDim.x + threadIdx.x;  // over float4 elements
    const int uelems = N_USERS * EMB / 4;
    const int total  = N_NODES * EMB / 4;
    if (i < total) {
        float4 v = (i < uelems) ? ((const float4*)ue)[i] : ((const float4*)ie)[i - uelems];
        ((float4*)embs)[i] = v;
        ((float4*)acc)[i]  = v;
    }
}

// ---------------- SpMM (CSR gather): out[r] = dinv[r] * sum_e dinv[col] * embs[col] ----
// One wave per row, lane = dim. Coalesced 256B row gathers, no atomics.

__global__ __launch_bounds__(256) void spmm_csr_kernel(const int* __restrict__ row_ptr,
                                                       const int* __restrict__ col,
                                                       const float* __restrict__ dinv,
                                                       const float* __restrict__ embs,
                                                       float* __restrict__ out) {
    int wave = threadIdx.x >> 6;
    int lane = threadIdx.x & 63;
    int row = blockIdx.x * 4 + wave;          // grid exactly covers 150000
    int s = row_ptr[row], e = row_ptr[row + 1];
    float dr = dinv[row];
    float acc = 0.0f;
    int i = s;
    for (; i + 1 < e; i += 2) {               // 2-way unroll for load overlap
        int c0 = col[i], c1 = col[i + 1];
        float g0 = dinv[c0], g1 = dinv[c1];
        float v0 = embs[(size_t)c0 * EMB + lane];
        float v1 = embs[(size_t)c1 * EMB + lane];
        acc = fmaf(g0, v0, acc);
        acc = fmaf(g1, v1, acc);
    }
    if (i < e) {
        int c0 = col[i];
        acc = fmaf(dinv[c0], embs[(size_t)c0 * EMB + lane], acc);
    }
    out[(size_t)row * EMB + lane] = acc * dr;
}

// ---------------- intent head + combine ----------------

__global__ __launch_bounds__(256) void intent_kernel(const float* __restrict__ W,
                                                     const float* __restrict__ gnn,
                                                     float* __restrict__ embs,
                                                     float* __restrict__ acc,
                                                     float scale) {
    __shared__ float Wt[NI * 65];    // Wt[c*65+d] = W[d*128+c]
    __shared__ float esm[4][EMB];
    __shared__ float pr[4][NI];

    for (int i = threadIdx.x; i < EMB * NI; i += blockDim.x) {
        int d = i >> 7, c = i & 127;
        Wt[c * 65 + d] = W[i];
    }
    __syncthreads();

    int wave = threadIdx.x >> 6;
    int lane = threadIdx.x & 63;
    int row  = blockIdx.x * 4 + wave;

    esm[wave][lane] = embs[row * EMB + lane];
    __syncthreads();

    float s0 = 0.0f, s1 = 0.0f;
    const float* w0 = &Wt[lane * 65];
    const float* w1 = &Wt[(lane + 64) * 65];
    const float* er = esm[wave];
#pragma unroll 8
    for (int d = 0; d < EMB; ++d) {
        float ed = er[d];
        s0 = fmaf(ed, w0[d], s0);
        s1 = fmaf(ed, w1[d], s1);
    }

    float m = fmaxf(s0, s1);
    for (int o = 32; o > 0; o >>= 1) m = fmaxf(m, __shfl_xor(m, o));
    float e0 = __expf(s0 - m), e1 = __expf(s1 - m);
    float sum = e0 + e1;
    for (int o = 32; o > 0; o >>= 1) sum += __shfl_xor(sum, o);
    float inv = 1.0f / sum;
    pr[wave][lane]      = e0 * inv;
    pr[wave][lane + 64] = e1 * inv;
    __syncthreads();

    float o = 0.0f;
    const float* pw = pr[wave];
#pragma unroll 8
    for (int c = 0; c < NI; ++c) o = fmaf(pw[c], Wt[c * 65 + lane], o);

    int idx = row * EMB + lane;
    float nv = gnn[idx] + o;
    embs[idx] = nv;
    acc[idx] = (acc[idx] + nv) * scale;
}

// ---------------- launch ----------------

extern "C" void kernel_launch(void* const* d_in, const int* in_sizes, int n_in,
                              void* d_out, int out_size, void* d_ws, size_t ws_size,
                              hipStream_t stream) {
    const float* ue = (const float*)d_in[0];
    const float* ie = (const float*)d_in[1];
    const float* W  = (const float*)d_in[2];
    const int*   h  = (const int*)d_in[3];
    const int*   t  = (const int*)d_in[4];
    float* out = (float*)d_out;

    // workspace layout (4B elements)
    int*   cnt     = (int*)d_ws;                  // NPAD
    int*   row_ptr = cnt + NPAD;                  // NPAD + 16
    int*   cursor  = row_ptr + NPAD + 16;         // NPAD
    int*   bsum    = cursor + NPAD;               // 1024
    float* dinv    = (float*)(bsum + 1024);       // NPAD
    int*   col     = (int*)(dinv + NPAD);         // 4,000,000
    float* embs    = (float*)(col + NUM_EDGES);   // 9,600,000
    float* gnn     = embs + (size_t)N_NODES * EMB;// 9,600,000

    hipMemsetAsync(cnt, 0, NPAD * sizeof(int), stream);
    count_kernel<<<(NUM_EDGES + 255) / 256, 256, 0, stream>>>(h, cnt);
    blocksum_kernel<<<NBLK, 256, 0, stream>>>(cnt, bsum);
    scanpart_kernel<<<1, 1024, 0, stream>>>(bsum);
    finalize_kernel<<<NBLK, 256, 0, stream>>>(cnt, bsum, row_ptr, cursor, dinv);
    scatter_kernel<<<(NUM_EDGES + 255) / 256, 256, 0, stream>>>(h, t, cursor, col);
    init_kernel<<<(N_NODES * EMB / 4 + 255) / 256, 256, 0, stream>>>(ue, ie, embs, out);

    for (int layer = 0; layer < 2; ++layer) {
        spmm_csr_kernel<<<N_NODES / 4, 256, 0, stream>>>(row_ptr, col, dinv, embs, gnn);
        float scale = (layer == 1) ? (1.0f / 3.0f) : 1.0f;
        intent_kernel<<<N_NODES / 4, 256, 0, stream>>>(W, gnn, embs, out, scale);
    }
}